// Round 19
// baseline (757.300 us; speedup 1.0000x reference)
//
#include <hip/hip_runtime.h>
#include <hip/hip_bf16.h>
#include <stdint.h>

// ---- problem constants ----
#define B_      2
#define N_      2048
#define S_      2049          // tokens incl. cls
#define SP_     2176          // padded tokens per batch (17*128)
#define MP_     (B_*SP_)      // 4352 = 34*128
#define IN_DIM_ 1024
#define DIM_    512
#define HEADS_  8
#define DH_     128
#define INNER_  1024
#define MLP_    1024
#define DEPTH_  4
#define NKV_    33            // KV tiles with any real content (j<2112)
#define NCHUNK_ 2
#define TPC_    17            // KV tiles per chunk (17,16)
// 1/sqrt(128) * log2(e): Q pre-scale so softmax runs in base-2 with no muls
#define QSCALE_ 0.1275256405f

typedef __bf16 bf16;
typedef __bf16 bf16x4 __attribute__((ext_vector_type(4)));
typedef __bf16 bf16x8 __attribute__((ext_vector_type(8)));
typedef float  f32x4  __attribute__((ext_vector_type(4)));

// native v_exp_f32 (base-2). exp2f() w/o builtin lowers to precise libm
// (~10 VALU ops) — R17's regression. This is 1 instruction.
__device__ __forceinline__ float fexp2(float x) { return __builtin_amdgcn_exp2f(x); }

#define AS1 __attribute__((address_space(1)))
#define AS3 __attribute__((address_space(3)))
// async global->LDS, 16B/lane; LDS dest = wave-uniform base + lane*16
__device__ __forceinline__ void gload16(const bf16* g, bf16* l) {
    __builtin_amdgcn_global_load_lds((const AS1 void*)g, (AS3 void*)l, 16, 0, 0);
}

// ---------------------------------------------------------------------------
// Weight convert + transpose: src [L][K][N] f32 -> dst [L][N][K] bf16
// ---------------------------------------------------------------------------
__global__ __launch_bounds__(256) void wconv_kernel(const float* __restrict__ src,
                                                    bf16* __restrict__ dst,
                                                    int K, int N)
{
    __shared__ float tile[32][33];
    size_t mo = (size_t)blockIdx.z * K * N;
    int n0 = blockIdx.x * 32, k0 = blockIdx.y * 32;
    int tx = threadIdx.x & 31, ty = threadIdx.x >> 5;   // 32 x 8
#pragma unroll
    for (int i = 0; i < 32; i += 8)
        tile[ty + i][tx] = src[mo + (size_t)(k0 + ty + i) * N + n0 + tx];
    __syncthreads();
#pragma unroll
    for (int i = 0; i < 32; i += 8)
        dst[mo + (size_t)(n0 + ty + i) * K + k0 + tx] = (bf16)tile[tx][ty + i];
}

// ---------------------------------------------------------------------------
// x (B,N,IN) f32 -> x_bf (B,SP,IN) bf16 with row 0 + pad rows zeroed
// ---------------------------------------------------------------------------
__global__ __launch_bounds__(256) void xconv_kernel(const float* __restrict__ x,
                                                    bf16* __restrict__ xb)
{
    int idx = blockIdx.x * 256 + threadIdx.x;    // MP_*IN_DIM_/8 items
    int row = idx >> 7;                          // IN_DIM_/8 = 128 groups/row
    int c   = (idx & 127) * 8;
    int b = row / SP_, s = row - b * SP_;
    bf16x8 v;
    if (s >= 1 && s <= N_) {
        const float* src = x + (size_t)(b * N_ + s - 1) * IN_DIM_ + c;
#pragma unroll
        for (int i = 0; i < 8; ++i) v[i] = (bf16)src[i];
    } else {
#pragma unroll
        for (int i = 0; i < 8; ++i) v[i] = (bf16)0.f;
    }
    *(bf16x8*)&xb[(size_t)row * IN_DIM_ + c] = v;
}

// ---------------------------------------------------------------------------
// mask (B,N) -> additive bias pb (B,SP) IN LOG2 UNITS: 0 keep, -1.44e30 drop
// ---------------------------------------------------------------------------
__global__ __launch_bounds__(256) void mask_kernel(const float* __restrict__ mask,
                                                   float* __restrict__ pb)
{
    int j = blockIdx.x * 256 + threadIdx.x;
    int b = blockIdx.y;
    if (j >= SP_) return;
    float v;
    if (j == 0) v = 0.f;
    else if (j <= N_) v = (mask[(size_t)b * N_ + j - 1] != 0.f) ? 0.f : -1.442695e30f;
    else v = -1.442695e30f;
    pb[(size_t)b * SP_ + j] = v;
}

// ---------------------------------------------------------------------------
// cls token -> h row 0 of each batch (f32)
// ---------------------------------------------------------------------------
__global__ void cls_kernel(const float* __restrict__ cls, float* __restrict__ h)
{
    h[(size_t)(blockIdx.x * SP_) * DIM_ + threadIdx.x] = cls[threadIdx.x];
}

// ---------------------------------------------------------------------------
// LayerNorm over DIM_=512, one wave per row, f32 in -> bf16 out
// ---------------------------------------------------------------------------
__global__ __launch_bounds__(256) void ln_kernel(const float* __restrict__ h,
                                                 const float* __restrict__ g,
                                                 const float* __restrict__ bta,
                                                 bf16* __restrict__ out)
{
    int row  = blockIdx.x * 4 + (threadIdx.x >> 6);
    int lane = threadIdx.x & 63;
    const float* x = h + (size_t)row * DIM_;
    float v[8]; float s = 0.f;
#pragma unroll
    for (int i = 0; i < 8; ++i) { v[i] = x[lane + 64 * i]; s += v[i]; }
#pragma unroll
    for (int o = 32; o; o >>= 1) s += __shfl_xor(s, o);
    float mean = s * (1.f / DIM_);
    float vs = 0.f;
#pragma unroll
    for (int i = 0; i < 8; ++i) { float d = v[i] - mean; vs += d * d; }
#pragma unroll
    for (int o = 32; o; o >>= 1) vs += __shfl_xor(vs, o);
    float rstd = rsqrtf(vs * (1.f / DIM_) + 1e-5f);
    bf16* orow = out + (size_t)row * DIM_;
#pragma unroll
    for (int i = 0; i < 8; ++i)
        orow[lane + 64 * i] = (bf16)((v[i] - mean) * rstd * g[lane + 64 * i] + bta[lane + 64 * i]);
}

// ---------------------------------------------------------------------------
// GEMM (m97 structure): C = act(A * Bt^T + bias), bf16 in, fp32 acc.
// ACT: 0=none 1=relu 2=gelu 3=scale-Q-columns (col<INNER_) by QSCALE_.
// SKIPPAD: grid-x remap skipping all-pad 64-row M-tiles 33 & 67.
// ---------------------------------------------------------------------------
template<int BM, int BN, int BK, int ACT, int OUTBF, int SKIPPAD>
__global__ __launch_bounds__(256) void gemm_bt(const bf16* __restrict__ A,
                                               const bf16* __restrict__ Bt,
                                               const float* __restrict__ bias,
                                               void* __restrict__ Cp,
                                               int M, int N, int K)
{
    constexpr int MF  = (BM == 128) ? 4 : ((BN == 128) ? 4 : 2);
    constexpr int NF  = (BM == 128) ? 4 : 2;
    constexpr int ACH = BM * BK / 512;   // 1KB chunks for A tile
    constexpr int BCH = BN * BK / 512;
    constexpr int LPR = BK / 8;          // lanes covering one row
    constexpr int RPC = 512 / BK;        // rows per 1KB chunk
    constexpr int KM  = LPR - 1;         // swizzle row mask
    __shared__ __align__(16) bf16 As[BM * BK];
    __shared__ __align__(16) bf16 Bs[BN * BK];
    const int tid  = threadIdx.x;
    const int wave = tid >> 6, lane = tid & 63;
    int bxi = blockIdx.x;
    if (SKIPPAD) bxi += (bxi >= 33);     // 0..32, 34..66 (skip tiles 33 & 67)
    const int bm = bxi * BM, bn = blockIdx.y * BN;
    const int wr = (BM == 128) ? (wave >> 1) * 64 : ((BN == 64) ? (wave >> 1) * 32 : 0);
    const int wc = (BM == 128) ? (wave & 1) * 64 : ((BN == 64) ? (wave & 1) * 32 : wave * 32);
    const int fr = lane & 15, fk = (lane >> 4) * 8;
    const int gr = lane / LPR, gc = (lane % LPR) * 8;

    f32x4 acc[MF][NF];
#pragma unroll
    for (int m = 0; m < MF; ++m)
#pragma unroll
        for (int n = 0; n < NF; ++n) acc[m][n] = (f32x4){0.f, 0.f, 0.f, 0.f};

    for (int k0 = 0; k0 < K; k0 += BK) {
#pragma unroll
        for (int t = 0; t < ACH / 4; ++t) {
            int chunk = wave * (ACH / 4) + t;
            int r = chunk * RPC + gr;
            gload16(&A[(size_t)(bm + r) * K + k0 + (gc ^ ((r & KM) << 3))], &As[chunk * 512]);
        }
#pragma unroll
        for (int t = 0; t < BCH / 4; ++t) {
            int chunk = wave * (BCH / 4) + t;
            int r = chunk * RPC + gr;
            gload16(&Bt[(size_t)(bn + r) * K + k0 + (gc ^ ((r & KM) << 3))], &Bs[chunk * 512]);
        }
        __syncthreads();   // vmcnt drained -> tiles resident
#pragma unroll
        for (int kk = 0; kk < BK / 32; ++kk) {
            bf16x8 af[MF], bb[NF];
#pragma unroll
            for (int m = 0; m < MF; ++m) {
                int r = wr + m * 16 + fr;
                af[m] = *(const bf16x8*)&As[r * BK + ((kk * 32 + fk) ^ ((r & KM) << 3))];
            }
#pragma unroll
            for (int n = 0; n < NF; ++n) {
                int r = wc + n * 16 + fr;
                bb[n] = *(const bf16x8*)&Bs[r * BK + ((kk * 32 + fk) ^ ((r & KM) << 3))];
            }
#pragma unroll
            for (int m = 0; m < MF; ++m)
#pragma unroll
                for (int n = 0; n < NF; ++n)
                    acc[m][n] = __builtin_amdgcn_mfma_f32_16x16x32_bf16(af[m], bb[n], acc[m][n], 0, 0, 0);
        }
        __syncthreads();   // all reads done before next stage overwrites
    }

    const int fc = lane & 15, fr4 = (lane >> 4) * 4;
#pragma unroll
    for (int n = 0; n < NF; ++n) {
        int col = bn + wc + n * 16 + fc;
        float bv = bias ? bias[col] : 0.f;
#pragma unroll
        for (int m = 0; m < MF; ++m) {
#pragma unroll
            for (int j = 0; j < 4; ++j) {
                int row = bm + wr + m * 16 + fr4 + j;
                float v = acc[m][n][j] + bv;
                if (ACT == 1) v = fmaxf(v, 0.f);
                if (ACT == 2) v = 0.5f * v * (1.f + erff(v * 0.70710678118654752f));
                if (ACT == 3 && col < INNER_) v *= QSCALE_;   // pre-scale Q
                if (OUTBF) ((bf16*)Cp)[(size_t)row * N + col] = (bf16)v;
                else       ((float*)Cp)[(size_t)row * N + col] = v;
            }
        }
    }
}

// ---------------------------------------------------------------------------
// Flash attention, KV-split: grid (B*HEADS, 33, NCHUNK_=2). 4 waves x 16 q.
// 2 chunks (17/16 KV tiles): halves partial-O write traffic + combine reads
// + per-block prologues vs NCHUNK=4, while 1056 blocks still ~fill the
// 4-blocks/CU residency. Base-2 softmax with native v_exp_f32.
// NO occupancy directives (launch_bounds(,3)/waves_per_eu -> 84-reg spill).
// ---------------------------------------------------------------------------
__global__ __launch_bounds__(256) void attn_kernel(const bf16* __restrict__ qkv,
                                                   const float* __restrict__ pb,
                                                   bf16* __restrict__ o0,
                                                   bf16* __restrict__ o1,
                                                   float* __restrict__ mlbuf)
{
    __shared__ __align__(16) bf16 Ks[64 * 128];     // [j][k], key=(r&15)<<3 (gload)
    __shared__ __align__(16) bf16 Vt[128 * 64];     // [d][j], key=((d&7)^((d>>3)&7))<<3
    __shared__ __align__(16) bf16 Ps[4][16 * 64];   // per-wave [q][j], key=(q&7)<<3

    const int bh = blockIdx.x, b = bh >> 3, hh = bh & 7;
    const int q0 = blockIdx.y * 64;
    const int chunk = blockIdx.z;
    const int t0 = chunk * TPC_;
    const int t1 = (t0 + TPC_ < NKV_) ? t0 + TPC_ : NKV_;
    bf16* obuf = (chunk == 0) ? o0 : o1;

    const int tid = threadIdx.x, wave = tid >> 6, lane = tid & 63;
    const int fc = lane & 15, g = lane >> 4, g8 = g * 8, rr0 = g * 4;
    bf16* Pw = &Ps[wave][0];

    const bf16* qb  = qkv + (size_t)(b * SP_) * (3 * INNER_) + hh * DH_;
    const bf16* kb  = qb + INNER_;
    const bf16* vb  = qb + 2 * INNER_;
    const float* pbb = pb + (size_t)b * SP_;

    // Q fragments in registers (B-operand: lane&15 = q, k = g*8+i)
    bf16x8 aq[4];
#pragma unroll
    for (int kk = 0; kk < 4; ++kk)
        aq[kk] = *(const bf16x8*)&qb[(size_t)(q0 + wave * 16 + fc) * (3 * INNER_) + kk * 32 + g8];

    f32x4 accO[8];
#pragma unroll
    for (int f = 0; f < 8; ++f) accO[f] = (f32x4){0.f, 0.f, 0.f, 0.f};
    float mrow = -3e38f;
    float lrow = 0.f;

    // K tile: 16 chunks of 1KB via global_load_lds; pre-swizzled source.
    auto issueK = [&](int kt) {
        int j0 = kt * 64;
#pragma unroll
        for (int t = 0; t < 4; ++t) {
            int ck = wave * 4 + t;
            int r = ck * 4 + (lane >> 4);
            int cp = (lane & 15) * 8;
            gload16(&kb[(size_t)(j0 + r) * (3 * INNER_) + (cp ^ ((r & 15) << 3))], &Ks[ck * 512]);
        }
    };
    // V: thread loads 4 consecutive rows at d-block vd8 (for quad-pack transpose)
    const int vquad = tid >> 4;         // 0..15
    const int vd8   = (tid & 15) * 8;
    bf16x8 vreg[4];
    auto issueV = [&](int kt) {
        int j0 = kt * 64;
#pragma unroll
        for (int i = 0; i < 4; ++i)
            vreg[i] = *(const bf16x8*)&vb[(size_t)(j0 + vquad * 4 + i) * (3 * INNER_) + vd8];
    };

    issueK(t0);
    issueV(t0);
    for (int kt = t0; kt < t1; ++kt) {
        int j0 = kt * 64;
        __syncthreads();    // B1: prev tile consumed; K gloads drained -> Ks resident
#pragma unroll
        for (int di = 0; di < 8; ++di) {
            int rd = vd8 + di;
            bf16x4 w = { vreg[0][di], vreg[1][di], vreg[2][di], vreg[3][di] };
            *(bf16x4*)&Vt[rd * 64 + ((vquad * 4) ^ ((((rd & 7) ^ ((rd >> 3) & 7))) << 3))] = w;
        }
        __syncthreads();    // B2: Vt staged
        if (kt + 1 < t1) issueV(kt + 1);   // V loads fly under QK (vreg free now)

        // ---- S^T = K · Q^T : lane holds S[j = f*16+rr0+r][q = fc] ----
        f32x4 sf[4];
#pragma unroll
        for (int f = 0; f < 4; ++f) sf[f] = (f32x4){0.f, 0.f, 0.f, 0.f};
        __builtin_amdgcn_s_setprio(1);
#pragma unroll
        for (int kk = 0; kk < 4; ++kk) {
            bf16x8 bk[4];
#pragma unroll
            for (int f = 0; f < 4; ++f) {
                int r = f * 16 + fc;
                bk[f] = *(const bf16x8*)&Ks[r * 128 + ((kk * 32 + g8) ^ ((r & 15) << 3))];
            }
#pragma unroll
            for (int f = 0; f < 4; ++f)
                sf[f] = __builtin_amdgcn_mfma_f32_16x16x32_bf16(bk[f], aq[kk], sf[f], 0, 0, 0);
        }
        __builtin_amdgcn_s_setprio(0);
        __syncthreads();    // B3: all waves done reading Ks
        if (kt + 1 < t1) issueK(kt + 1);   // K gloads fly under softmax + PV

        // ---- online softmax in base-2 (per-q stats live at lane&15 = q) ----
        float rmax = -3e38f;
#pragma unroll
        for (int f = 0; f < 4; ++f) {
            f32x4 mb = *(const f32x4*)&pbb[j0 + f * 16 + rr0];
#pragma unroll
            for (int r = 0; r < 4; ++r) {
                float s = sf[f][r] + mb[r];
                sf[f][r] = s;
                rmax = fmaxf(rmax, s);
            }
        }
        rmax = fmaxf(rmax, __shfl_xor(rmax, 16));
        rmax = fmaxf(rmax, __shfl_xor(rmax, 32));
        if (__any(rmax > mrow + 7.22f)) {   // T13 defer-max (5 nats = 7.22 bits)
            float mn = fmaxf(mrow, rmax);
            float corr = fexp2(mrow - mn);
            mrow = mn;
            lrow *= corr;
            float c0 = __shfl(corr, rr0 + 0);
            float c1 = __shfl(corr, rr0 + 1);
            float c2 = __shfl(corr, rr0 + 2);
            float c3 = __shfl(corr, rr0 + 3);
#pragma unroll
            for (int f = 0; f < 8; ++f) {
                accO[f][0] *= c0; accO[f][1] *= c1;
                accO[f][2] *= c2; accO[f][3] *= c3;
            }
        }
        // P = exp2(S - m) via native v_exp_f32 -> per-wave LDS
#pragma unroll
        for (int f = 0; f < 4; ++f) {
            bf16x4 pw;
#pragma unroll
            for (int r = 0; r < 4; ++r) {
                float p = fexp2(sf[f][r] - mrow);
                lrow += p;
                pw[r] = (bf16)p;
            }
            *(bf16x4*)&Pw[fc * 64 + ((f * 16 + rr0) ^ ((fc & 7) << 3))] = pw;
        }
        // ---- O += P · V ----
        __builtin_amdgcn_s_setprio(1);
#pragma unroll
        for (int kk = 0; kk < 2; ++kk) {
            bf16x8 ap = *(const bf16x8*)&Pw[fc * 64 + ((kk * 32 + g8) ^ ((fc & 7) << 3))];
#pragma unroll
            for (int f = 0; f < 8; ++f) {
                int rd = f * 16 + fc;
                bf16x8 bv = *(const bf16x8*)&Vt[rd * 64 + ((kk * 32 + g8) ^ ((((rd & 7) ^ ((rd >> 3) & 7))) << 3))];
                accO[f] = __builtin_amdgcn_mfma_f32_16x16x32_bf16(ap, bv, accO[f], 0, 0, 0);
            }
        }
        __builtin_amdgcn_s_setprio(0);
    }

    // ---- finalize: l-reduce over j-groups, write normalized partial O + (m,l) ----
    {
        float l = lrow;
        l += __shfl_xor(l, 16);
        l += __shfl_xor(l, 32);
        if (g == 0) {
            int q = q0 + wave * 16 + fc;
            size_t mi = ((size_t)(chunk * B_ * HEADS_ + bh) * SP_ + q) * 2;
            mlbuf[mi + 0] = mrow;
            mlbuf[mi + 1] = l;
        }
        float linv = (l > 0.f) ? 1.f / l : 0.f;
        float l0 = __shfl(linv, rr0 + 0);
        float l1 = __shfl(linv, rr0 + 1);
        float l2 = __shfl(linv, rr0 + 2);
        float l3 = __shfl(linv, rr0 + 3);
#pragma unroll
        for (int f = 0; f < 8; ++f) {
            int col = hh * DH_ + f * 16 + fc;
            size_t base = (size_t)(b * SP_ + q0 + wave * 16 + rr0) * INNER_ + col;
            obuf[base + 0 * INNER_] = (bf16)(accO[f][0] * l0);
            obuf[base + 1 * INNER_] = (bf16)(accO[f][1] * l1);
            obuf[base + 2 * INNER_] = (bf16)(accO[f][2] * l2);
            obuf[base + 3 * INNER_] = (bf16)(accO[f][3] * l3);
        }
    }
}

// ---------------------------------------------------------------------------
// Combine 2 KV-split partials (base-2 stats): o_final = w0*O0 + w1*O1.
// q >= 2112 -> write zeros (attn skipped the all-pad tile).
// ---------------------------------------------------------------------------
__global__ __launch_bounds__(256) void attn_combine_kernel(const bf16* __restrict__ o0,
                                                           bf16* __restrict__ o1,
                                                           const float* __restrict__ mlbuf)
{
    const int bh = blockIdx.y, b = bh >> 3, hh = bh & 7;
    int gx = blockIdx.x * 256 + threadIdx.x;    // SP_ * 16 items per bh
    int q  = gx >> 4;
    int d  = (gx & 15) * 8;
    size_t base = (size_t)(b * SP_ + q) * INNER_ + hh * DH_ + d;

    if (q >= 2112) {
        bf16x8 z;
#pragma unroll
        for (int i = 0; i < 8; ++i) z[i] = (bf16)0.f;
        *(bf16x8*)&o1[base] = z;
        return;
    }

    size_t mi0 = ((size_t)(0 * B_ * HEADS_ + bh) * SP_ + q) * 2;
    size_t mi1 = ((size_t)(1 * B_ * HEADS_ + bh) * SP_ + q) * 2;
    float m0 = mlbuf[mi0], l0 = mlbuf[mi0 + 1];
    float m1 = mlbuf[mi1], l1 = mlbuf[mi1 + 1];
    float M = fmaxf(m0, m1);
    float w0 = l0 * __builtin_amdgcn_exp2f(m0 - M);
    float w1 = l1 * __builtin_amdgcn_exp2f(m1 - M);
    float den = w0 + w1;
    float r = (den > 0.f) ? 1.f / den : 0.f;
    w0 *= r; w1 *= r;

    bf16x8 v0 = *(const bf16x8*)&o0[base];
    bf16x8 v1 = *(const bf16x8*)&o1[base];
    bf16x8 out;
#pragma unroll
    for (int i = 0; i < 8; ++i)
        out[i] = (bf16)(w0 * (float)v0[i] + w1 * (float)v1[i]);
    *(bf16x8*)&o1[base] = out;
}

// ---------------------------------------------------------------------------
// Head: pooled = h[:,0]; LN(norm) -> LN(head_ln) -> @ head_w + head_b
// ---------------------------------------------------------------------------
__global__ __launch_bounds__(64) void head_kernel(const float* __restrict__ h,
                                                  const float* __restrict__ ng, const float* __restrict__ nb,
                                                  const float* __restrict__ hg, const float* __restrict__ hb,
                                                  const float* __restrict__ hw, const float* __restrict__ hbi,
                                                  float* __restrict__ out)
{
    int b = blockIdx.x, lane = threadIdx.x;
    const float* xr = h + (size_t)(b * SP_) * DIM_;
    float v[8]; float s = 0.f;
#pragma unroll
    for (int i = 0; i < 8; ++i) { v[i] = xr[lane + 64 * i]; s += v[i]; }
#pragma unroll
    for (int o = 32; o; o >>= 1) s += __shfl_xor(s, o);
    float mean = s * (1.f / DIM_); float vs = 0.f;
#pragma unroll
    for (int i = 0; i < 8; ++i) { float d = v[i] - mean; vs += d * d; }
#pragma unroll
    for (int o = 32; o; o >>= 1) vs += __shfl_xor(vs, o);
    float rstd = rsqrtf(vs * (1.f / DIM_) + 1e-5f);
#pragma unroll
    for (int i = 0; i < 8; ++i) v[i] = (v[i] - mean) * rstd * ng[lane + 64 * i] + nb[lane + 64 * i];
    s = 0.f;
#pragma unroll
    for (int i = 0; i < 8; ++i) s += v[i];
#pragma unroll
    for (int o = 32; o; o >>= 1) s += __shfl_xor(s, o);
    mean = s * (1.f / DIM_); vs = 0.f;
#pragma unroll
    for (int i = 0; i < 8; ++i) { float d = v[i] - mean; vs += d * d; }
#pragma unroll
    for (int o = 32; o; o >>= 1) vs += __shfl_xor(vs, o);
    rstd = rsqrtf(vs * (1.f / DIM_) + 1e-5f);
#pragma unroll
    for (int i = 0; i < 8; ++i) v[i] = (v[i] - mean) * rstd * hg[lane + 64 * i] + hb[lane + 64 * i];
    float a0 = 0.f, a1 = 0.f;
#pragma unroll
    for (int i = 0; i < 8; ++i) {
        a0 += v[i] * hw[(lane + 64 * i) * 2 + 0];
        a1 += v[i] * hw[(lane + 64 * i) * 2 + 1];
    }
#pragma unroll
    for (int o = 32; o; o >>= 1) { a0 += __shfl_xor(a0, o); a1 += __shfl_xor(a1, o); }
    if (lane == 0) { out[b * 2 + 0] = a0 + hbi[0]; out[b * 2 + 1] = a1 + hbi[1]; }
}

// ---------------------------------------------------------------------------
extern "C" void kernel_launch(void* const* d_in, const int* in_sizes, int n_in,
                              void* d_out, int out_size, void* d_ws, size_t ws_size,
                              hipStream_t stream)
{
    const float* x       = (const float*)d_in[0];
    const float* mask    = (const float*)d_in[1];
    const float* proj_w  = (const float*)d_in[2];
    const float* proj_b  = (const float*)d_in[3];
    const float* cls_tok = (const float*)d_in[4];
    const float* ln1_g   = (const float*)d_in[5];
    const float* ln1_b   = (const float*)d_in[6];
    const float* qkv_w   = (const float*)d_in[7];
    const float* out_w   = (const float*)d_in[8];
    const float* out_b   = (const float*)d_in[9];
    const float* ln2_g   = (const float*)d_in[10];
    const float* ln2_b   = (const float*)d_in[11];
    const float* ff_w1   = (const float*)d_in[12];
    const float* ff_b1   = (const float*)d_in[13];
    const float* ff_w2   = (const float*)d_in[14];
    const float* ff_b2   = (const float*)d_in[15];
    const float* norm_g  = (const float*)d_in[16];
    const float* norm_b  = (const float*)d_in[17];
    const float* hln_g   = (const float*)d_in[18];
    const float* hln_b   = (const float*)d_in[19];
    const float* head_w  = (const float*)d_in[20];
    const float* head_b  = (const float*)d_in[21];

    char* p = (char*)d_ws;
    auto alloc = [&](size_t bytes) { char* r = p; p += (bytes + 255) & ~(size_t)255; return r; };
    bf16*  x_bf    = (bf16*)alloc((size_t)MP_ * IN_DIM_ * 2);   // dead after proj -> attn chunk0
    float* h       = (float*)alloc((size_t)MP_ * DIM_ * 4);
    bf16*  hn_bf   = (bf16*)alloc((size_t)MP_ * DIM_ * 2);      // dead during attn -> mlbuf
    bf16*  qkv_bf  = (bf16*)alloc((size_t)MP_ * 3 * INNER_ * 2);
    bf16*  o_bf    = (bf16*)alloc((size_t)MP_ * INNER_ * 2);    // attn chunk1 + final O
    bf16*  ff1_bf  = (bf16*)alloc((size_t)MP_ * MLP_ * 2);
    bf16*  proj_wt = (bf16*)alloc((size_t)DIM_ * IN_DIM_ * 2);
    bf16*  qkv_wt  = (bf16*)alloc((size_t)DEPTH_ * 3 * INNER_ * DIM_ * 2);
    bf16*  out_wt  = (bf16*)alloc((size_t)DEPTH_ * DIM_ * INNER_ * 2);
    bf16*  ff1_wt  = (bf16*)alloc((size_t)DEPTH_ * MLP_ * DIM_ * 2);
    bf16*  ff2_wt  = (bf16*)alloc((size_t)DEPTH_ * DIM_ * MLP_ * 2);
    float* pbias   = (float*)alloc((size_t)B_ * SP_ * 4);
    if ((size_t)(p - (char*)d_ws) > ws_size) return;
    float* mlbuf = (float*)hn_bf;   // NCHUNK_*16*SP_*2 f32 = 0.56 MB <= 4.45 MB

    // weights -> bf16 [N][K]
    wconv_kernel<<<dim3(DIM_ / 32, IN_DIM_ / 32, 1), 256, 0, stream>>>(proj_w, proj_wt, IN_DIM_, DIM_);
    wconv_kernel<<<dim3(3 * INNER_ / 32, DIM_ / 32, DEPTH_), 256, 0, stream>>>(qkv_w, qkv_wt, DIM_, 3 * INNER_);
    wconv_kernel<<<dim3(DIM_ / 32, INNER_ / 32, DEPTH_), 256, 0, stream>>>(out_w, out_wt, INNER_, DIM_);
    wconv_kernel<<<dim3(MLP_ / 32, DIM_ / 32, DEPTH_), 256, 0, stream>>>(ff_w1, ff1_wt, DIM_, MLP_);
    wconv_kernel<<<dim3(DIM_ / 32, MLP_ / 32, DEPTH_), 256, 0, stream>>>(ff_w2, ff2_wt, MLP_, DIM_);

    xconv_kernel<<<MP_ * IN_DIM_ / 8 / 256, 256, 0, stream>>>(x, x_bf);
    mask_kernel<<<dim3((SP_ + 255) / 256, B_), 256, 0, stream>>>(mask, pbias);

    gemm_bt<64, 64, 128, 1, 0, 1><<<dim3(66, DIM_ / 64), 256, 0, stream>>>(x_bf, proj_wt, proj_b, h, MP_, DIM_, IN_DIM_);
    cls_kernel<<<B_, DIM_, 0, stream>>>(cls_tok, h);

    for (int l = 0; l < DEPTH_; ++l) {
        ln_kernel<<<MP_ / 4, 256, 0, stream>>>(h, ln1_g + l * DIM_, ln1_b + l * DIM_, hn_bf);
        gemm_bt<128, 128, 64, 3, 1, 0><<<dim3(MP_ / 128, 3 * INNER_ / 128), 256, 0, stream>>>(
            hn_bf, qkv_wt + (size_t)l * 3 * INNER_ * DIM_, nullptr, qkv_bf, MP_, 3 * INNER_, DIM_);
        attn_kernel<<<dim3(B_ * HEADS_, 33, NCHUNK_), 256, 0, stream>>>(
            qkv_bf, pbias, x_bf, o_bf, mlbuf);
        attn_combine_kernel<<<dim3(SP_ * 16 / 256, B_ * HEADS_), 256, 0, stream>>>(
            x_bf, o_bf, mlbuf);
        gemm_bt<64, 64, 128, 0, 0, 1><<<dim3(66, DIM_ / 64), 256, 0, stream>>>(
            o_bf, out_wt + (size_t)l * DIM_ * INNER_, out_b + l * DIM_, h, MP_, DIM_, INNER_);
        ln_kernel<<<MP_ / 4, 256, 0, stream>>>(h, ln2_g + l * DIM_, ln2_b + l * DIM_, hn_bf);
        gemm_bt<64, 128, 128, 2, 1, 1><<<dim3(66, MLP_ / 128), 256, 0, stream>>>(
            hn_bf, ff1_wt + (size_t)l * MLP_ * DIM_, ff_b1 + l * MLP_, ff1_bf, MP_, MLP_, DIM_);
        gemm_bt<64, 64, 128, 0, 0, 1><<<dim3(66, DIM_ / 64), 256, 0, stream>>>(
            ff1_bf, ff2_wt + (size_t)l * DIM_ * MLP_, ff_b2 + l * DIM_, h, MP_, DIM_, MLP_);
    }

    head_kernel<<<B_, 64, 0, stream>>>(h, norm_g, norm_b, hln_g, hln_b, head_w, head_b, (float*)d_out);
}

// Round 20
// 718.582 us; speedup vs baseline: 1.0539x; 1.0539x over previous
//
#include <hip/hip_runtime.h>
#include <hip/hip_bf16.h>
#include <stdint.h>

// ---- problem constants ----
#define B_      2
#define N_      2048
#define S_      2049          // tokens incl. cls
#define SP_     2176          // padded tokens per batch (17*128)
#define MP_     (B_*SP_)      // 4352 = 34*128
#define IN_DIM_ 1024
#define DIM_    512
#define HEADS_  8
#define DH_     128
#define INNER_  1024
#define MLP_    1024
#define DEPTH_  4
#define NKV_    33            // KV tiles with any real content (j<2112)
#define NCHUNK_ 4
#define TPC_    9             // KV tiles per chunk (9,9,9,6)
// 1/sqrt(128) * log2(e): Q pre-scale so softmax runs in base-2 with no muls
#define QSCALE_ 0.1275256405f

typedef __bf16 bf16;
typedef __bf16 bf16x4 __attribute__((ext_vector_type(4)));
typedef __bf16 bf16x8 __attribute__((ext_vector_type(8)));
typedef float  f32x4  __attribute__((ext_vector_type(4)));

// native v_exp_f32 (base-2). exp2f() without builtin lowers to the PRECISE
// libm path (~10 VALU ops) — that was R17's regression.
__device__ __forceinline__ float fexp2(float x) { return __builtin_amdgcn_exp2f(x); }

#define AS1 __attribute__((address_space(1)))
#define AS3 __attribute__((address_space(3)))
// async global->LDS, 16B/lane; LDS dest = wave-uniform base + lane*16
__device__ __forceinline__ void gload16(const bf16* g, bf16* l) {
    __builtin_amdgcn_global_load_lds((const AS1 void*)g, (AS3 void*)l, 16, 0, 0);
}

// ---------------------------------------------------------------------------
// Weight convert + transpose: src [L][K][N] f32 -> dst [L][N][K] bf16
// ---------------------------------------------------------------------------
__global__ __launch_bounds__(256) void wconv_kernel(const float* __restrict__ src,
                                                    bf16* __restrict__ dst,
                                                    int K, int N)
{
    __shared__ float tile[32][33];
    size_t mo = (size_t)blockIdx.z * K * N;
    int n0 = blockIdx.x * 32, k0 = blockIdx.y * 32;
    int tx = threadIdx.x & 31, ty = threadIdx.x >> 5;   // 32 x 8
#pragma unroll
    for (int i = 0; i < 32; i += 8)
        tile[ty + i][tx] = src[mo + (size_t)(k0 + ty + i) * N + n0 + tx];
    __syncthreads();
#pragma unroll
    for (int i = 0; i < 32; i += 8)
        dst[mo + (size_t)(n0 + ty + i) * K + k0 + tx] = (bf16)tile[tx][ty + i];
}

// ---------------------------------------------------------------------------
// x (B,N,IN) f32 -> x_bf (B,SP,IN) bf16 with row 0 + pad rows zeroed
// ---------------------------------------------------------------------------
__global__ __launch_bounds__(256) void xconv_kernel(const float* __restrict__ x,
                                                    bf16* __restrict__ xb)
{
    int idx = blockIdx.x * 256 + threadIdx.x;    // MP_*IN_DIM_/8 items
    int row = idx >> 7;                          // IN_DIM_/8 = 128 groups/row
    int c   = (idx & 127) * 8;
    int b = row / SP_, s = row - b * SP_;
    bf16x8 v;
    if (s >= 1 && s <= N_) {
        const float* src = x + (size_t)(b * N_ + s - 1) * IN_DIM_ + c;
#pragma unroll
        for (int i = 0; i < 8; ++i) v[i] = (bf16)src[i];
    } else {
#pragma unroll
        for (int i = 0; i < 8; ++i) v[i] = (bf16)0.f;
    }
    *(bf16x8*)&xb[(size_t)row * IN_DIM_ + c] = v;
}

// ---------------------------------------------------------------------------
// mask (B,N) -> additive bias pb (B,SP) IN LOG2 UNITS: 0 keep, -1.44e30 drop
// ---------------------------------------------------------------------------
__global__ __launch_bounds__(256) void mask_kernel(const float* __restrict__ mask,
                                                   float* __restrict__ pb)
{
    int j = blockIdx.x * 256 + threadIdx.x;
    int b = blockIdx.y;
    if (j >= SP_) return;
    float v;
    if (j == 0) v = 0.f;
    else if (j <= N_) v = (mask[(size_t)b * N_ + j - 1] != 0.f) ? 0.f : -1.442695e30f;
    else v = -1.442695e30f;
    pb[(size_t)b * SP_ + j] = v;
}

// ---------------------------------------------------------------------------
// cls token -> h row 0 of each batch (f32)
// ---------------------------------------------------------------------------
__global__ void cls_kernel(const float* __restrict__ cls, float* __restrict__ h)
{
    h[(size_t)(blockIdx.x * SP_) * DIM_ + threadIdx.x] = cls[threadIdx.x];
}

// ---------------------------------------------------------------------------
// LayerNorm over DIM_=512, one wave per row, f32 in -> bf16 out
// ---------------------------------------------------------------------------
__global__ __launch_bounds__(256) void ln_kernel(const float* __restrict__ h,
                                                 const float* __restrict__ g,
                                                 const float* __restrict__ bta,
                                                 bf16* __restrict__ out)
{
    int row  = blockIdx.x * 4 + (threadIdx.x >> 6);
    int lane = threadIdx.x & 63;
    const float* x = h + (size_t)row * DIM_;
    float v[8]; float s = 0.f;
#pragma unroll
    for (int i = 0; i < 8; ++i) { v[i] = x[lane + 64 * i]; s += v[i]; }
#pragma unroll
    for (int o = 32; o; o >>= 1) s += __shfl_xor(s, o);
    float mean = s * (1.f / DIM_);
    float vs = 0.f;
#pragma unroll
    for (int i = 0; i < 8; ++i) { float d = v[i] - mean; vs += d * d; }
#pragma unroll
    for (int o = 32; o; o >>= 1) vs += __shfl_xor(vs, o);
    float rstd = rsqrtf(vs * (1.f / DIM_) + 1e-5f);
    bf16* orow = out + (size_t)row * DIM_;
#pragma unroll
    for (int i = 0; i < 8; ++i)
        orow[lane + 64 * i] = (bf16)((v[i] - mean) * rstd * g[lane + 64 * i] + bta[lane + 64 * i]);
}

// ---------------------------------------------------------------------------
// GEMM (m97 structure): C = act(A * Bt^T + bias), bf16 in, fp32 acc.
// ACT: 0=none 1=relu 2=gelu 3=scale-Q-columns (col<INNER_) by QSCALE_.
// SKIPPAD: grid-x remap skipping all-pad 64-row M-tiles 33 & 67.
// ---------------------------------------------------------------------------
template<int BM, int BN, int BK, int ACT, int OUTBF, int SKIPPAD>
__global__ __launch_bounds__(256) void gemm_bt(const bf16* __restrict__ A,
                                               const bf16* __restrict__ Bt,
                                               const float* __restrict__ bias,
                                               void* __restrict__ Cp,
                                               int M, int N, int K)
{
    constexpr int MF  = (BM == 128) ? 4 : ((BN == 128) ? 4 : 2);
    constexpr int NF  = (BM == 128) ? 4 : 2;
    constexpr int ACH = BM * BK / 512;   // 1KB chunks for A tile
    constexpr int BCH = BN * BK / 512;
    constexpr int LPR = BK / 8;          // lanes covering one row
    constexpr int RPC = 512 / BK;        // rows per 1KB chunk
    constexpr int KM  = LPR - 1;         // swizzle row mask
    __shared__ __align__(16) bf16 As[BM * BK];
    __shared__ __align__(16) bf16 Bs[BN * BK];
    const int tid  = threadIdx.x;
    const int wave = tid >> 6, lane = tid & 63;
    int bxi = blockIdx.x;
    if (SKIPPAD) bxi += (bxi >= 33);     // 0..32, 34..66 (skip tiles 33 & 67)
    const int bm = bxi * BM, bn = blockIdx.y * BN;
    const int wr = (BM == 128) ? (wave >> 1) * 64 : ((BN == 64) ? (wave >> 1) * 32 : 0);
    const int wc = (BM == 128) ? (wave & 1) * 64 : ((BN == 64) ? (wave & 1) * 32 : wave * 32);
    const int fr = lane & 15, fk = (lane >> 4) * 8;
    const int gr = lane / LPR, gc = (lane % LPR) * 8;

    f32x4 acc[MF][NF];
#pragma unroll
    for (int m = 0; m < MF; ++m)
#pragma unroll
        for (int n = 0; n < NF; ++n) acc[m][n] = (f32x4){0.f, 0.f, 0.f, 0.f};

    for (int k0 = 0; k0 < K; k0 += BK) {
#pragma unroll
        for (int t = 0; t < ACH / 4; ++t) {
            int chunk = wave * (ACH / 4) + t;
            int r = chunk * RPC + gr;
            gload16(&A[(size_t)(bm + r) * K + k0 + (gc ^ ((r & KM) << 3))], &As[chunk * 512]);
        }
#pragma unroll
        for (int t = 0; t < BCH / 4; ++t) {
            int chunk = wave * (BCH / 4) + t;
            int r = chunk * RPC + gr;
            gload16(&Bt[(size_t)(bn + r) * K + k0 + (gc ^ ((r & KM) << 3))], &Bs[chunk * 512]);
        }
        __syncthreads();   // vmcnt drained -> tiles resident
#pragma unroll
        for (int kk = 0; kk < BK / 32; ++kk) {
            bf16x8 af[MF], bb[NF];
#pragma unroll
            for (int m = 0; m < MF; ++m) {
                int r = wr + m * 16 + fr;
                af[m] = *(const bf16x8*)&As[r * BK + ((kk * 32 + fk) ^ ((r & KM) << 3))];
            }
#pragma unroll
            for (int n = 0; n < NF; ++n) {
                int r = wc + n * 16 + fr;
                bb[n] = *(const bf16x8*)&Bs[r * BK + ((kk * 32 + fk) ^ ((r & KM) << 3))];
            }
#pragma unroll
            for (int m = 0; m < MF; ++m)
#pragma unroll
                for (int n = 0; n < NF; ++n)
                    acc[m][n] = __builtin_amdgcn_mfma_f32_16x16x32_bf16(af[m], bb[n], acc[m][n], 0, 0, 0);
        }
        __syncthreads();   // all reads done before next stage overwrites
    }

    const int fc = lane & 15, fr4 = (lane >> 4) * 4;
#pragma unroll
    for (int n = 0; n < NF; ++n) {
        int col = bn + wc + n * 16 + fc;
        float bv = bias ? bias[col] : 0.f;
#pragma unroll
        for (int m = 0; m < MF; ++m) {
#pragma unroll
            for (int j = 0; j < 4; ++j) {
                int row = bm + wr + m * 16 + fr4 + j;
                float v = acc[m][n][j] + bv;
                if (ACT == 1) v = fmaxf(v, 0.f);
                if (ACT == 2) v = 0.5f * v * (1.f + erff(v * 0.70710678118654752f));
                if (ACT == 3 && col < INNER_) v *= QSCALE_;   // pre-scale Q
                if (OUTBF) ((bf16*)Cp)[(size_t)row * N + col] = (bf16)v;
                else       ((float*)Cp)[(size_t)row * N + col] = v;
            }
        }
    }
}

// ---------------------------------------------------------------------------
// Flash attention, KV-split: grid (B*HEADS, 33, NCHUNK_). 4 waves x 16 q.
// Softmax in BASE-2 with NATIVE v_exp_f32 (__builtin_amdgcn_exp2f): Q
// pre-scaled by scale*log2e, mask bias in log2 units -> s = qk + mb;
// p = native_exp2(s - m). 1 VALU op per P element (vs 2 for __expf, ~10 for
// libm exp2f — R17's regression). VGPR ~100 -> 19% occupancy.
// NCHUNK=4 (2112 blocks): R19 showed NCHUNK=2's 1056 blocks leave a 32-block
// straggler tail — parallelism beats saved partial-O traffic here.
// NO occupancy directives (launch_bounds(,3)/waves_per_eu -> 84-reg spill).
// ---------------------------------------------------------------------------
__global__ __launch_bounds__(256) void attn_kernel(const bf16* __restrict__ qkv,
                                                   const float* __restrict__ pb,
                                                   bf16* __restrict__ o0,
                                                   bf16* __restrict__ o1,
                                                   bf16* __restrict__ o2,
                                                   bf16* __restrict__ o3,
                                                   float* __restrict__ mlbuf)
{
    __shared__ __align__(16) bf16 Ks[64 * 128];     // [j][k], key=(r&15)<<3 (gload)
    __shared__ __align__(16) bf16 Vt[128 * 64];     // [d][j], key=((d&7)^((d>>3)&7))<<3
    __shared__ __align__(16) bf16 Ps[4][16 * 64];   // per-wave [q][j], key=(q&7)<<3

    const int bh = blockIdx.x, b = bh >> 3, hh = bh & 7;
    const int q0 = blockIdx.y * 64;
    const int chunk = blockIdx.z;
    const int t0 = chunk * TPC_;
    const int t1 = (t0 + TPC_ < NKV_) ? t0 + TPC_ : NKV_;
    bf16* obuf = (chunk == 0) ? o0 : (chunk == 1) ? o1 : (chunk == 2) ? o2 : o3;

    const int tid = threadIdx.x, wave = tid >> 6, lane = tid & 63;
    const int fc = lane & 15, g = lane >> 4, g8 = g * 8, rr0 = g * 4;
    bf16* Pw = &Ps[wave][0];

    const bf16* qb  = qkv + (size_t)(b * SP_) * (3 * INNER_) + hh * DH_;
    const bf16* kb  = qb + INNER_;
    const bf16* vb  = qb + 2 * INNER_;
    const float* pbb = pb + (size_t)b * SP_;

    // Q fragments in registers (B-operand: lane&15 = q, k = g*8+i)
    bf16x8 aq[4];
#pragma unroll
    for (int kk = 0; kk < 4; ++kk)
        aq[kk] = *(const bf16x8*)&qb[(size_t)(q0 + wave * 16 + fc) * (3 * INNER_) + kk * 32 + g8];

    f32x4 accO[8];
#pragma unroll
    for (int f = 0; f < 8; ++f) accO[f] = (f32x4){0.f, 0.f, 0.f, 0.f};
    float mrow = -3e38f;
    float lrow = 0.f;

    // K tile: 16 chunks of 1KB via global_load_lds; pre-swizzled source.
    auto issueK = [&](int kt) {
        int j0 = kt * 64;
#pragma unroll
        for (int t = 0; t < 4; ++t) {
            int ck = wave * 4 + t;
            int r = ck * 4 + (lane >> 4);
            int cp = (lane & 15) * 8;
            gload16(&kb[(size_t)(j0 + r) * (3 * INNER_) + (cp ^ ((r & 15) << 3))], &Ks[ck * 512]);
        }
    };
    // V: thread loads 4 consecutive rows at d-block vd8 (for quad-pack transpose)
    const int vquad = tid >> 4;         // 0..15
    const int vd8   = (tid & 15) * 8;
    bf16x8 vreg[4];
    auto issueV = [&](int kt) {
        int j0 = kt * 64;
#pragma unroll
        for (int i = 0; i < 4; ++i)
            vreg[i] = *(const bf16x8*)&vb[(size_t)(j0 + vquad * 4 + i) * (3 * INNER_) + vd8];
    };

    issueK(t0);
    issueV(t0);
    for (int kt = t0; kt < t1; ++kt) {
        int j0 = kt * 64;
        __syncthreads();    // B1: prev tile consumed; K gloads drained -> Ks resident
#pragma unroll
        for (int di = 0; di < 8; ++di) {
            int rd = vd8 + di;
            bf16x4 w = { vreg[0][di], vreg[1][di], vreg[2][di], vreg[3][di] };
            *(bf16x4*)&Vt[rd * 64 + ((vquad * 4) ^ ((((rd & 7) ^ ((rd >> 3) & 7))) << 3))] = w;
        }
        __syncthreads();    // B2: Vt staged
        if (kt + 1 < t1) issueV(kt + 1);   // V loads fly under QK (vreg free now)

        // ---- S^T = K · Q^T : lane holds S[j = f*16+rr0+r][q = fc] ----
        f32x4 sf[4];
#pragma unroll
        for (int f = 0; f < 4; ++f) sf[f] = (f32x4){0.f, 0.f, 0.f, 0.f};
        __builtin_amdgcn_s_setprio(1);
#pragma unroll
        for (int kk = 0; kk < 4; ++kk) {
            bf16x8 bk[4];
#pragma unroll
            for (int f = 0; f < 4; ++f) {
                int r = f * 16 + fc;
                bk[f] = *(const bf16x8*)&Ks[r * 128 + ((kk * 32 + g8) ^ ((r & 15) << 3))];
            }
#pragma unroll
            for (int f = 0; f < 4; ++f)
                sf[f] = __builtin_amdgcn_mfma_f32_16x16x32_bf16(bk[f], aq[kk], sf[f], 0, 0, 0);
        }
        __builtin_amdgcn_s_setprio(0);
        __syncthreads();    // B3: all waves done reading Ks
        if (kt + 1 < t1) issueK(kt + 1);   // K gloads fly under softmax + PV

        // ---- online softmax in base-2 (per-q stats live at lane&15 = q) ----
        float rmax = -3e38f;
#pragma unroll
        for (int f = 0; f < 4; ++f) {
            f32x4 mb = *(const f32x4*)&pbb[j0 + f * 16 + rr0];
#pragma unroll
            for (int r = 0; r < 4; ++r) {
                float s = sf[f][r] + mb[r];
                sf[f][r] = s;
                rmax = fmaxf(rmax, s);
            }
        }
        rmax = fmaxf(rmax, __shfl_xor(rmax, 16));
        rmax = fmaxf(rmax, __shfl_xor(rmax, 32));
        if (__any(rmax > mrow + 7.22f)) {   // T13 defer-max (5 nats = 7.22 bits)
            float mn = fmaxf(mrow, rmax);
            float corr = fexp2(mrow - mn);
            mrow = mn;
            lrow *= corr;
            float c0 = __shfl(corr, rr0 + 0);
            float c1 = __shfl(corr, rr0 + 1);
            float c2 = __shfl(corr, rr0 + 2);
            float c3 = __shfl(corr, rr0 + 3);
#pragma unroll
            for (int f = 0; f < 8; ++f) {
                accO[f][0] *= c0; accO[f][1] *= c1;
                accO[f][2] *= c2; accO[f][3] *= c3;
            }
        }
        // P = exp2(S - m) via native v_exp_f32 -> per-wave LDS
#pragma unroll
        for (int f = 0; f < 4; ++f) {
            bf16x4 pw;
#pragma unroll
            for (int r = 0; r < 4; ++r) {
                float p = fexp2(sf[f][r] - mrow);
                lrow += p;
                pw[r] = (bf16)p;
            }
            *(bf16x4*)&Pw[fc * 64 + ((f * 16 + rr0) ^ ((fc & 7) << 3))] = pw;
        }
        // ---- O += P · V ----
        __builtin_amdgcn_s_setprio(1);
#pragma unroll
        for (int kk = 0; kk < 2; ++kk) {
            bf16x8 ap = *(const bf16x8*)&Pw[fc * 64 + ((kk * 32 + g8) ^ ((fc & 7) << 3))];
#pragma unroll
            for (int f = 0; f < 8; ++f) {
                int rd = f * 16 + fc;
                bf16x8 bv = *(const bf16x8*)&Vt[rd * 64 + ((kk * 32 + g8) ^ ((((rd & 7) ^ ((rd >> 3) & 7))) << 3))];
                accO[f] = __builtin_amdgcn_mfma_f32_16x16x32_bf16(ap, bv, accO[f], 0, 0, 0);
            }
        }
        __builtin_amdgcn_s_setprio(0);
    }

    // ---- finalize: l-reduce over j-groups, write normalized partial O + (m,l) ----
    {
        float l = lrow;
        l += __shfl_xor(l, 16);
        l += __shfl_xor(l, 32);
        if (g == 0) {
            int q = q0 + wave * 16 + fc;
            size_t mi = ((size_t)(chunk * B_ * HEADS_ + bh) * SP_ + q) * 2;
            mlbuf[mi + 0] = mrow;
            mlbuf[mi + 1] = l;
        }
        float linv = (l > 0.f) ? 1.f / l : 0.f;
        float l0 = __shfl(linv, rr0 + 0);
        float l1 = __shfl(linv, rr0 + 1);
        float l2 = __shfl(linv, rr0 + 2);
        float l3 = __shfl(linv, rr0 + 3);
#pragma unroll
        for (int f = 0; f < 8; ++f) {
            int col = hh * DH_ + f * 16 + fc;
            size_t base = (size_t)(b * SP_ + q0 + wave * 16 + rr0) * INNER_ + col;
            obuf[base + 0 * INNER_] = (bf16)(accO[f][0] * l0);
            obuf[base + 1 * INNER_] = (bf16)(accO[f][1] * l1);
            obuf[base + 2 * INNER_] = (bf16)(accO[f][2] * l2);
            obuf[base + 3 * INNER_] = (bf16)(accO[f][3] * l3);
        }
    }
}

// ---------------------------------------------------------------------------
// Combine KV-split partials (base-2 stats): o_final = sum_c w_c * O_c.
// q >= 2112 -> write zeros (attn skipped the all-pad tile).
// ---------------------------------------------------------------------------
__global__ __launch_bounds__(256) void attn_combine_kernel(const bf16* __restrict__ o0,
                                                           const bf16* __restrict__ o1,
                                                           const bf16* __restrict__ o2,
                                                           bf16* __restrict__ o3,
                                                           const float* __restrict__ mlbuf)
{
    const int bh = blockIdx.y, b = bh >> 3, hh = bh & 7;
    int gx = blockIdx.x * 256 + threadIdx.x;    // SP_ * 16 items per bh
    int q  = gx >> 4;
    int d  = (gx & 15) * 8;
    size_t base = (size_t)(b * SP_ + q) * INNER_ + hh * DH_ + d;

    if (q >= 2112) {
        bf16x8 z;
#pragma unroll
        for (int i = 0; i < 8; ++i) z[i] = (bf16)0.f;
        *(bf16x8*)&o3[base] = z;
        return;
    }

    float mv[NCHUNK_], lv[NCHUNK_];
#pragma unroll
    for (int c = 0; c < NCHUNK_; ++c) {
        size_t mi = ((size_t)(c * B_ * HEADS_ + bh) * SP_ + q) * 2;
        mv[c] = mlbuf[mi];
        lv[c] = mlbuf[mi + 1];
    }
    float M = mv[0];
#pragma unroll
    for (int c = 1; c < NCHUNK_; ++c) M = fmaxf(M, mv[c]);
    float w[NCHUNK_], den = 0.f;
#pragma unroll
    for (int c = 0; c < NCHUNK_; ++c) { w[c] = lv[c] * __builtin_amdgcn_exp2f(mv[c] - M); den += w[c]; }
    float r = (den > 0.f) ? 1.f / den : 0.f;

    bf16x8 v0 = *(const bf16x8*)&o0[base];
    bf16x8 v1 = *(const bf16x8*)&o1[base];
    bf16x8 v2 = *(const bf16x8*)&o2[base];
    bf16x8 v3 = *(const bf16x8*)&o3[base];
    bf16x8 out;
#pragma unroll
    for (int i = 0; i < 8; ++i)
        out[i] = (bf16)((w[0] * (float)v0[i] + w[1] * (float)v1[i]
                       + w[2] * (float)v2[i] + w[3] * (float)v3[i]) * r);
    *(bf16x8*)&o3[base] = out;
}

// ---------------------------------------------------------------------------
// Head: pooled = h[:,0]; LN(norm) -> LN(head_ln) -> @ head_w + head_b
// ---------------------------------------------------------------------------
__global__ __launch_bounds__(64) void head_kernel(const float* __restrict__ h,
                                                  const float* __restrict__ ng, const float* __restrict__ nb,
                                                  const float* __restrict__ hg, const float* __restrict__ hb,
                                                  const float* __restrict__ hw, const float* __restrict__ hbi,
                                                  float* __restrict__ out)
{
    int b = blockIdx.x, lane = threadIdx.x;
    const float* xr = h + (size_t)(b * SP_) * DIM_;
    float v[8]; float s = 0.f;
#pragma unroll
    for (int i = 0; i < 8; ++i) { v[i] = xr[lane + 64 * i]; s += v[i]; }
#pragma unroll
    for (int o = 32; o; o >>= 1) s += __shfl_xor(s, o);
    float mean = s * (1.f / DIM_); float vs = 0.f;
#pragma unroll
    for (int i = 0; i < 8; ++i) { float d = v[i] - mean; vs += d * d; }
#pragma unroll
    for (int o = 32; o; o >>= 1) vs += __shfl_xor(vs, o);
    float rstd = rsqrtf(vs * (1.f / DIM_) + 1e-5f);
#pragma unroll
    for (int i = 0; i < 8; ++i) v[i] = (v[i] - mean) * rstd * ng[lane + 64 * i] + nb[lane + 64 * i];
    s = 0.f;
#pragma unroll
    for (int i = 0; i < 8; ++i) s += v[i];
#pragma unroll
    for (int o = 32; o; o >>= 1) s += __shfl_xor(s, o);
    mean = s * (1.f / DIM_); vs = 0.f;
#pragma unroll
    for (int i = 0; i < 8; ++i) { float d = v[i] - mean; vs += d * d; }
#pragma unroll
    for (int o = 32; o; o >>= 1) vs += __shfl_xor(vs, o);
    rstd = rsqrtf(vs * (1.f / DIM_) + 1e-5f);
#pragma unroll
    for (int i = 0; i < 8; ++i) v[i] = (v[i] - mean) * rstd * hg[lane + 64 * i] + hb[lane + 64 * i];
    float a0 = 0.f, a1 = 0.f;
#pragma unroll
    for (int i = 0; i < 8; ++i) {
        a0 += v[i] * hw[(lane + 64 * i) * 2 + 0];
        a1 += v[i] * hw[(lane + 64 * i) * 2 + 1];
    }
#pragma unroll
    for (int o = 32; o; o >>= 1) { a0 += __shfl_xor(a0, o); a1 += __shfl_xor(a1, o); }
    if (lane == 0) { out[b * 2 + 0] = a0 + hbi[0]; out[b * 2 + 1] = a1 + hbi[1]; }
}

// ---------------------------------------------------------------------------
extern "C" void kernel_launch(void* const* d_in, const int* in_sizes, int n_in,
                              void* d_out, int out_size, void* d_ws, size_t ws_size,
                              hipStream_t stream)
{
    const float* x       = (const float*)d_in[0];
    const float* mask    = (const float*)d_in[1];
    const float* proj_w  = (const float*)d_in[2];
    const float* proj_b  = (const float*)d_in[3];
    const float* cls_tok = (const float*)d_in[4];
    const float* ln1_g   = (const float*)d_in[5];
    const float* ln1_b   = (const float*)d_in[6];
    const float* qkv_w   = (const float*)d_in[7];
    const float* out_w   = (const float*)d_in[8];
    const float* out_b   = (const float*)d_in[9];
    const float* ln2_g   = (const float*)d_in[10];
    const float* ln2_b   = (const float*)d_in[11];
    const float* ff_w1   = (const float*)d_in[12];
    const float* ff_b1   = (const float*)d_in[13];
    const float* ff_w2   = (const float*)d_in[14];
    const float* ff_b2   = (const float*)d_in[15];
    const float* norm_g  = (const float*)d_in[16];
    const float* norm_b  = (const float*)d_in[17];
    const float* hln_g   = (const float*)d_in[18];
    const float* hln_b   = (const float*)d_in[19];
    const float* head_w  = (const float*)d_in[20];
    const float* head_b  = (const float*)d_in[21];

    char* p = (char*)d_ws;
    auto alloc = [&](size_t bytes) { char* r = p; p += (bytes + 255) & ~(size_t)255; return r; };
    bf16*  x_bf    = (bf16*)alloc((size_t)MP_ * IN_DIM_ * 2);   // dead after proj -> attn chunk0
    float* h       = (float*)alloc((size_t)MP_ * DIM_ * 4);     // dead during attn -> chunk2
    bf16*  hn_bf   = (bf16*)alloc((size_t)MP_ * DIM_ * 2);      // dead during attn -> mlbuf
    bf16*  qkv_bf  = (bf16*)alloc((size_t)MP_ * 3 * INNER_ * 2);
    bf16*  o_bf    = (bf16*)alloc((size_t)MP_ * INNER_ * 2);    // attn chunk3 + final O
    bf16*  ff1_bf  = (bf16*)alloc((size_t)MP_ * MLP_ * 2);      // dead during attn -> chunk1
    bf16*  proj_wt = (bf16*)alloc((size_t)DIM_ * IN_DIM_ * 2);
    bf16*  qkv_wt  = (bf16*)alloc((size_t)DEPTH_ * 3 * INNER_ * DIM_ * 2);
    bf16*  out_wt  = (bf16*)alloc((size_t)DEPTH_ * DIM_ * INNER_ * 2);
    bf16*  ff1_wt  = (bf16*)alloc((size_t)DEPTH_ * MLP_ * DIM_ * 2);
    bf16*  ff2_wt  = (bf16*)alloc((size_t)DEPTH_ * DIM_ * MLP_ * 2);
    float* pbias   = (float*)alloc((size_t)B_ * SP_ * 4);
    if ((size_t)(p - (char*)d_ws) > ws_size) return;
    float* mlbuf = (float*)hn_bf;   // NCHUNK_*16*SP_*2 f32 = 1.1 MB <= 4.45 MB

    // weights -> bf16 [N][K]
    wconv_kernel<<<dim3(DIM_ / 32, IN_DIM_ / 32, 1), 256, 0, stream>>>(proj_w, proj_wt, IN_DIM_, DIM_);
    wconv_kernel<<<dim3(3 * INNER_ / 32, DIM_ / 32, DEPTH_), 256, 0, stream>>>(qkv_w, qkv_wt, DIM_, 3 * INNER_);
    wconv_kernel<<<dim3(DIM_ / 32, INNER_ / 32, DEPTH_), 256, 0, stream>>>(out_w, out_wt, INNER_, DIM_);
    wconv_kernel<<<dim3(MLP_ / 32, DIM_ / 32, DEPTH_), 256, 0, stream>>>(ff_w1, ff1_wt, DIM_, MLP_);
    wconv_kernel<<<dim3(DIM_ / 32, MLP_ / 32, DEPTH_), 256, 0, stream>>>(ff_w2, ff2_wt, MLP_, DIM_);

    xconv_kernel<<<MP_ * IN_DIM_ / 8 / 256, 256, 0, stream>>>(x, x_bf);
    mask_kernel<<<dim3((SP_ + 255) / 256, B_), 256, 0, stream>>>(mask, pbias);

    gemm_bt<64, 64, 128, 1, 0, 1><<<dim3(66, DIM_ / 64), 256, 0, stream>>>(x_bf, proj_wt, proj_b, h, MP_, DIM_, IN_DIM_);
    cls_kernel<<<B_, DIM_, 0, stream>>>(cls_tok, h);

    for (int l = 0; l < DEPTH_; ++l) {
        ln_kernel<<<MP_ / 4, 256, 0, stream>>>(h, ln1_g + l * DIM_, ln1_b + l * DIM_, hn_bf);
        gemm_bt<128, 128, 64, 3, 1, 0><<<dim3(MP_ / 128, 3 * INNER_ / 128), 256, 0, stream>>>(
            hn_bf, qkv_wt + (size_t)l * 3 * INNER_ * DIM_, nullptr, qkv_bf, MP_, 3 * INNER_, DIM_);
        attn_kernel<<<dim3(B_ * HEADS_, 33, NCHUNK_), 256, 0, stream>>>(
            qkv_bf, pbias, x_bf, ff1_bf, (bf16*)h, o_bf, mlbuf);
        attn_combine_kernel<<<dim3(SP_ * 16 / 256, B_ * HEADS_), 256, 0, stream>>>(
            x_bf, ff1_bf, (const bf16*)h, o_bf, mlbuf);
        gemm_bt<64, 64, 128, 0, 0, 1><<<dim3(66, DIM_ / 64), 256, 0, stream>>>(
            o_bf, out_wt + (size_t)l * DIM_ * INNER_, out_b + l * DIM_, h, MP_, DIM_, INNER_);
        ln_kernel<<<MP_ / 4, 256, 0, stream>>>(h, ln2_g + l * DIM_, ln2_b + l * DIM_, hn_bf);
        gemm_bt<64, 128, 128, 2, 1, 1><<<dim3(66, MLP_ / 128), 256, 0, stream>>>(
            hn_bf, ff1_wt + (size_t)l * MLP_ * DIM_, ff_b1 + l * MLP_, ff1_bf, MP_, MLP_, DIM_);
        gemm_bt<64, 64, 128, 0, 0, 1><<<dim3(66, DIM_ / 64), 256, 0, stream>>>(
            ff1_bf, ff2_wt + (size_t)l * DIM_ * MLP_, ff_b2 + l * DIM_, h, MP_, DIM_, MLP_);
    }

    head_kernel<<<B_, 64, 0, stream>>>(h, norm_g, norm_b, hln_g, hln_b, head_w, head_b, (float*)d_out);
}